// Round 16
// baseline (1105.849 us; speedup 1.0000x reference)
//
#include <hip/hip_runtime.h>
#include <cstdint>
#include <cstddef>

#define B_ 128
#define T_ 8192
#define F_ 10
#define F1_ 8
#define H1_ 8
#define H2_ 7
#define K_ 16
#define CHUNK 64
#define NC (T_/CHUNK)   // 128

#define LOG2E 1.4426950408889634f

__device__ __forceinline__ float exp2_fast(float x){ float r; asm("v_exp_f32 %0, %1" : "=v"(r) : "v"(x)); return r; }
__device__ __forceinline__ float rcp_fast(float x){ float r; asm("v_rcp_f32 %0, %1" : "=v"(r) : "v"(x)); return r; }
template<int CTRL>
__device__ __forceinline__ float dppf(float x){
  return __int_as_float(__builtin_amdgcn_update_dpp(0, __float_as_int(x), CTRL, 0xF, 0xF, true));
}
// row_ror:m -> lane i reads lane (i-m)&15; on 8-periodic data = h[(u-m)&7].
// Weights indexed (u+8-m)&7 (direction validated r9->r10).
#define ROR(m) (0x120+(m))
#define WIDX(u,m) (((u)+8-(m))&7)
__device__ __forceinline__ float ror8(float x){ return dppf<0x128>(x); }
typedef int v2i_t __attribute__((ext_vector_type(2)));

// Burst rings: ROW STRIDE 12 floats (48B, 16B-aligned, <=2-way banks; r15).
#define GSTRIDE 12
#define GBURST  (32*GSTRIDE)
#define GCHUNK  (8*GBURST)
#define FSTRIDE 12
#define FBURST  (64*FSTRIDE)
#define FCHUNK  (8*FBURST)

// ---------------- Kernel 2: 6-wave pipelined fused network -----------------
// Wave->SIMD (round-robin by wave id): SIMD0: wv0=C + wv4=E (helpers);
// SIMD1: wv1=D + wv5=F (consumers, TLP pair); SIMD2: wv2=A (chain, alone);
// SIMD3: wv3=B (chain, alone).
// C: tanh(h1)+W_ih2 -> ff ring.  E: conv+W_ih1 -> g1 ring.
// A: LSTM1 recurrence -> h1 ring.  B: LSTM2 recurrence -> h2 ring.
// D: tanh(h2) -> z stores + fused S.  F: fq (rotate-reduce) + xr stores.
// r12/r14 showed fq+xr serial-in-D paces the barrier (latency-bound);
// r16 splits it into wave F so D/F overlap via TLP on SIMD1 (~120cyc
// issue combined < chains' 209cyc pace).
// Rings depth-2 by chunk parity. Iteration k: E makes g1[k], A makes
// h1[k-1], C makes ff[k-2], B makes h2[k-3], D/F consume h2[k-4].
// One lgkmcnt(0)+s_barrier per iteration, all 6 waves.
__global__ __launch_bounds__(384,1) void k2_lstm(
    const float* __restrict__ x,
    const float* __restrict__ conv_w, const float* __restrict__ conv_b,
    const float* __restrict__ w_ih1, const float* __restrict__ b_ih1,
    const float* __restrict__ b_hh1, const float* __restrict__ w_hh1,
    const float* __restrict__ w_ih2, const float* __restrict__ w_hh2,
    const float* __restrict__ b_ih2, const float* __restrict__ b_hh2,
    const float* __restrict__ centers,
    const float* __restrict__ dec_w, const float* __restrict__ dec_b,
    float* __restrict__ zout, float* __restrict__ xrg,
    float* __restrict__ fqg, float* __restrict__ Sws)
{
  __shared__ float h1r[2*CHUNK*64];   // 32 KB raw h1  [slot][s][lane]
  __shared__ float ffr[2*FCHUNK];     // 48 KB ff      str12 burst-major
  __shared__ float h2r[2*CHUNK*64];   // 32 KB raw h2  [slot][s][lane]
  __shared__ float g1r[2*GCHUNK];     // 24 KB g1 pre  str12 burst-major
  __shared__ float esc[64];           // E's enc exchange scratch
  const int b = blockIdx.x;
  const int tid = threadIdx.x;
  const int wv = tid >> 6;
  const int lane = tid & 63;
  const int u = lane & 7;
  const bool c2 = (lane >> 3) & 1;
  const bool up = (lane >> 5) & 1;
  const bool isg = (c2 && !up);
  const float A2 = isg ? (-2.f*LOG2E) : 0.5f;
  const float D_ = isg ? ( 2.f*LOG2E) : 0.f;
  const float Sx = isg ? (-2.f*LOG2E) : (-LOG2E);

  if (wv == 2){
    // ---------------- Wave A: LSTM1 recurrence (SIMD2, alone) --------------
    const int prow = u + (c2 ? 16 : 0) + (up ? 8 : 0);     // W1 rows i|f|g|o
    float wp[8];
    #pragma unroll
    for (int m=0;m<8;++m) wp[m] = w_hh1[prow*8 + WIDX(u,m)] * Sx;
    float hq=0.f, csq=0.f;
    for (int k=0;k<NC+4;++k){
      if (k>=1 && k<NC+1){
        const int ck = k-1;
        const float* g1p = &g1r[(ck&1)*GCHUNK];
        float* hp = &h1r[(ck&1)*CHUNK*64];
        float4 cA = *(const float4*)&g1p[prow*GSTRIDE];
        float4 cB = *(const float4*)&g1p[prow*GSTRIDE+4];
        for (int j=0;j<8;++j){
          const int jn = (j<7) ? j+1 : 7;
          float4 nA = *(const float4*)&g1p[jn*GBURST + prow*GSTRIDE];
          float4 nB = *(const float4*)&g1p[jn*GBURST + prow*GSTRIDE+4];
          #pragma unroll
          for (int si=0;si<8;++si){
            const int s = (j<<3)+si;
            float pre = (si<4) ? (&cA.x)[si] : (&cB.x)[si-4];
            float x1 = dppf<ROR(1)>(hq);
            float x2 = dppf<ROR(2)>(hq);
            float x3 = dppf<ROR(3)>(hq);
            float x4 = dppf<ROR(4)>(hq);
            float x5 = dppf<ROR(5)>(hq);
            float x6 = dppf<ROR(6)>(hq);
            float x7 = dppf<ROR(7)>(hq);
            float A0 = fmaf(wp[0], hq, pre);
            A0 = fmaf(wp[4], x4, A0);
            float p2 = wp[2]*x2;
            float p3 = wp[3]*x3;
            A0 = fmaf(wp[1], x1, A0);
            float P2 = fmaf(wp[6], x6, p2);
            float P3 = fmaf(wp[7], x7, p3);
            float p5 = wp[5]*x5;
            A0 = A0 + p5;
            float g = A0 + (P2+P3);
            float e = exp2_fast(g);
            float tg = fmaf(e, 0.5f, 0.5f);
            float r = rcp_fast(tg);
            float y = fmaf(A2, r, D_);
            v2i_t pr = __builtin_amdgcn_permlane32_swap(__float_as_int(y), __float_as_int(y), false, false);
            float lov = __int_as_float(pr.x);
            float hiv = __int_as_float(pr.y);
            float IG = lov * ror8(lov);
            float HR = ror8(hiv);
            float Fv = c2 ? HR : hiv;
            float Ov = c2 ? hiv : HR;
            float cs = fmaf(Fv, csq, IG);
            float e2 = exp2_fast(cs);
            float t2 = fmaf(e2, 0.5f, 0.5f);
            float r2v = rcp_fast(t2);
            float hn = fmaf(Ov, r2v, -Ov);
            csq = cs; hq = hn;
            hp[(s<<6)+lane] = hn;
          }
          cA = nA; cB = nB;
        }
      }
      asm volatile("s_waitcnt lgkmcnt(0)\ns_barrier" ::: "memory");
    }
  } else if (wv == 3){
    // ---------------- Wave B: LSTM2 recurrence (SIMD3, alone) --------------
    const int r2 = u + (c2 ? 14 : 0) + (up ? 7 : 0);       // W2 rows (H2=7)
    float wb[8];
    #pragma unroll
    for (int m=0;m<8;++m) wb[m] = 0.f;
    if (u < 7){
      #pragma unroll
      for (int m=0;m<8;++m){
        int jm = WIDX(u,m);
        wb[m] = (jm<7) ? w_hh2[r2*7+jm]*Sx : 0.f;
      }
    }
    float hq=0.f, csq=0.f;
    for (int k=0;k<NC+4;++k){
      if (k>=3 && k<NC+3){
        const int ck = k-3;
        const float* fp_ = &ffr[(ck&1)*FCHUNK];
        float* hp = &h2r[(ck&1)*CHUNK*64];
        float4 cA = *(const float4*)&fp_[lane*FSTRIDE];
        float4 cB = *(const float4*)&fp_[lane*FSTRIDE+4];
        for (int j=0;j<8;++j){
          const int jn = (j<7) ? j+1 : 7;
          float4 nA = *(const float4*)&fp_[jn*FBURST + lane*FSTRIDE];
          float4 nB = *(const float4*)&fp_[jn*FBURST + lane*FSTRIDE+4];
          #pragma unroll
          for (int si=0;si<8;++si){
            const int s = (j<<3)+si;
            float ffv = (si<4) ? (&cA.x)[si] : (&cB.x)[si-4];
            float x1 = dppf<ROR(1)>(hq);
            float x2 = dppf<ROR(2)>(hq);
            float x3 = dppf<ROR(3)>(hq);
            float x4 = dppf<ROR(4)>(hq);
            float x5 = dppf<ROR(5)>(hq);
            float x6 = dppf<ROR(6)>(hq);
            float x7 = dppf<ROR(7)>(hq);
            float A0 = fmaf(wb[0], hq, ffv);
            A0 = fmaf(wb[4], x4, A0);
            float p2 = wb[2]*x2;
            float p3 = wb[3]*x3;
            A0 = fmaf(wb[1], x1, A0);
            float P2 = fmaf(wb[6], x6, p2);
            float P3 = fmaf(wb[7], x7, p3);
            float p5 = wb[5]*x5;
            A0 = A0 + p5;
            float g = A0 + (P2+P3);
            float e = exp2_fast(g);
            float tg = fmaf(e, 0.5f, 0.5f);
            float r = rcp_fast(tg);
            float y = fmaf(A2, r, D_);
            v2i_t pr = __builtin_amdgcn_permlane32_swap(__float_as_int(y), __float_as_int(y), false, false);
            float lov = __int_as_float(pr.x);
            float hiv = __int_as_float(pr.y);
            float IG = lov * ror8(lov);
            float HR = ror8(hiv);
            float Fv = c2 ? HR : hiv;
            float Ov = c2 ? hiv : HR;
            float cs = fmaf(Fv, csq, IG);
            float e2 = exp2_fast(cs);
            float t2 = fmaf(e2, 0.5f, 0.5f);
            float r2v = rcp_fast(t2);
            float hn = fmaf(Ov, r2v, -Ov);
            csq = cs; hq = hn;
            hp[(s<<6)+lane] = hn;
          }
          cA = nA; cB = nB;
        }
      }
      asm volatile("s_waitcnt lgkmcnt(0)\ns_barrier" ::: "memory");
    }
  } else if (wv == 0){
    // ---------------- Wave C: ff projection from h1 (SIMD0) ----------------
    const int r2 = u + (c2 ? 14 : 0) + (up ? 7 : 0);
    float wff[8]; float pre2C = 0.f;
    #pragma unroll
    for (int m=0;m<8;++m) wff[m] = 0.f;
    if (u < 7){
      #pragma unroll
      for (int m=0;m<8;++m) wff[m] = w_ih2[r2*8 + WIDX(u,m)] * Sx;
      pre2C = (b_ih2[r2]+b_hh2[r2])*Sx;
    }
    for (int k=0;k<NC+4;++k){
      if (k>=2 && k<NC+2){
        const int ck = k-2;
        const float* h1p = &h1r[(ck&1)*CHUNK*64];
        float* ffp = &ffr[(ck&1)*FCHUNK];
        for (int s0=0;s0<CHUNK;s0+=8){
          #pragma unroll
          for (int si=0;si<8;++si){
            const int s = s0+si;
            float hv = h1p[(s<<6)+lane];
            float e3 = exp2_fast(hv * (-2.f*LOG2E));
            float t3 = fmaf(e3, 0.5f, 0.5f);
            float th = rcp_fast(t3) - 1.f;    // tanh(h1), replicated th[u]
            float f1 = dppf<ROR(1)>(th);
            float f2 = dppf<ROR(2)>(th);
            float f3 = dppf<ROR(3)>(th);
            float f4 = dppf<ROR(4)>(th);
            float f5 = dppf<ROR(5)>(th);
            float f6 = dppf<ROR(6)>(th);
            float f7 = dppf<ROR(7)>(th);
            float F0 = fmaf(wff[0], th, pre2C);
            F0 = fmaf(wff[4], f4, F0);
            float q2 = wff[2]*f2;
            float q3 = wff[3]*f3;
            F0 = fmaf(wff[1], f1, F0);
            q2 = fmaf(wff[6], f6, q2);
            q3 = fmaf(wff[7], f7, q3);
            float q5 = wff[5]*f5;
            F0 = F0 + q5;
            float ffv = F0 + (q2+q3);
            ffp[(s0>>3)*FBURST + lane*FSTRIDE + si] = ffv;
          }
        }
      }
      asm volatile("s_waitcnt lgkmcnt(0)\ns_barrier" ::: "memory");
    }
  } else if (wv == 1){
    // ---------------- Wave D: z stores + fused S (SIMD1) --------------------
    const int kk = lane & 15;
    float ckp[8]; float accS = 0.f;
    #pragma unroll
    for (int m=0;m<8;++m){
      int j = WIDX(u,m);
      ckp[m] = (j<7) ? centers[kk*H2_ + j] : 0.f;   // z_7 == 0 exactly
    }
    float* zb = zout + (size_t)b*T_*H2_;
    const int srow = lane >> 3;
    for (int k=0;k<NC+4;++k){
      if (k>=4 && k<NC+4){
        const int ck = k-4;
        const float* h2p = &h2r[(ck&1)*CHUNK*64];
        const int base_t = ck*CHUNK;
        for (int s0=0;s0<CHUNK;s0+=8){
          float zs[8];
          #pragma unroll
          for (int si=0;si<8;++si){
            float hv = h2p[((s0+si)<<6)+lane];
            float e3 = exp2_fast(hv * (-2.f*LOG2E));
            float t3 = fmaf(e3, 0.5f, 0.5f);
            float z = rcp_fast(t3) - 1.f;     // z = tanh(h2), replicated
            zs[si] = z;
            float z1 = dppf<ROR(1)>(z);
            float z2 = dppf<ROR(2)>(z);
            float z3 = dppf<ROR(3)>(z);
            float z4 = dppf<ROR(4)>(z);
            float z5 = dppf<ROR(5)>(z);
            float z6 = dppf<ROR(6)>(z);
            float z7 = dppf<ROR(7)>(z);
            float d = 1.f;
            float t0 = z  - ckp[0]; d = fmaf(t0,t0,d);
            float u1 = z1 - ckp[1]; d = fmaf(u1,u1,d);
            float u2 = z2 - ckp[2]; d = fmaf(u2,u2,d);
            float u3 = z3 - ckp[3]; d = fmaf(u3,u3,d);
            float u4 = z4 - ckp[4]; d = fmaf(u4,u4,d);
            float u5 = z5 - ckp[5]; d = fmaf(u5,u5,d);
            float u6 = z6 - ckp[6]; d = fmaf(u6,u6,d);
            float u7 = z7 - ckp[7]; d = fmaf(u7,u7,d);
            accS += rcp_fast(d);
          }
          float v0 = ((lane>>3)&1) ? zs[1] : zs[0];
          float v1 = ((lane>>3)&1) ? zs[3] : zs[2];
          float v2 = ((lane>>3)&1) ? zs[5] : zs[4];
          float v3 = ((lane>>3)&1) ? zs[7] : zs[6];
          float w0 = ((lane>>4)&1) ? v1 : v0;
          float w1 = ((lane>>4)&1) ? v3 : v2;
          float zo = ((lane>>5)&1) ? w1 : w0;
          if (u < 7) zb[(size_t)(base_t + s0 + srow)*H2_ + u] = zo;
        }
      }
      asm volatile("s_waitcnt lgkmcnt(0)\ns_barrier" ::: "memory");
    }
    if (lane < 16) Sws[b*K_ + lane] = accS;
  } else if (wv == 5){
    // ---------------- Wave F: fq + xr (SIMD1, pairs with D) -----------------
    // r12-validated fq/xr code (minus z/S), own wave for TLP.
    const int kk = lane & 15;
    float ckp[8];
    #pragma unroll
    for (int m=0;m<8;++m){
      int j = WIDX(u,m);
      ckp[m] = (j<7) ? centers[kk*H2_ + j] : 0.f;
    }
    float dw[8]; float xb = 0.f;
    #pragma unroll
    for (int m=0;m<8;++m){
      int j = WIDX(u,m);
      dw[m] = (j<7 && kk<10) ? dec_w[j*F_ + kk] : 0.f;
    }
    if (kk < 10) xb = dec_b[kk];
    float* fqb = fqg + (size_t)b*T_*K_;
    float* xrb = xrg + (size_t)b*T_*F_;
    const int fr = lane >> 4;
    for (int k=0;k<NC+4;++k){
      if (k>=4 && k<NC+4){
        const int ck = k-4;
        const float* h2p = &h2r[(ck&1)*CHUNK*64];
        const int base_t = ck*CHUNK;
        for (int s0=0;s0<CHUNK;s0+=8){
          float fqv[8], xv[8];
          #pragma unroll
          for (int si=0;si<8;++si){
            float hv = h2p[((s0+si)<<6)+lane];
            float e3 = exp2_fast(hv * (-2.f*LOG2E));
            float t3 = fmaf(e3, 0.5f, 0.5f);
            float z = rcp_fast(t3) - 1.f;     // z = tanh(h2), replicated
            float z1 = dppf<ROR(1)>(z);
            float z2 = dppf<ROR(2)>(z);
            float z3 = dppf<ROR(3)>(z);
            float z4 = dppf<ROR(4)>(z);
            float z5 = dppf<ROR(5)>(z);
            float z6 = dppf<ROR(6)>(z);
            float z7 = dppf<ROR(7)>(z);
            float d = 1.f;
            float t0 = z  - ckp[0]; d = fmaf(t0,t0,d);
            float u1 = z1 - ckp[1]; d = fmaf(u1,u1,d);
            float u2 = z2 - ckp[2]; d = fmaf(u2,u2,d);
            float u3 = z3 - ckp[3]; d = fmaf(u3,u3,d);
            float u4 = z4 - ckp[4]; d = fmaf(u4,u4,d);
            float u5 = z5 - ckp[5]; d = fmaf(u5,u5,d);
            float u6 = z6 - ckp[6]; d = fmaf(u6,u6,d);
            float u7 = z7 - ckp[7]; d = fmaf(u7,u7,d);
            float Qv = rcp_fast(d);
            // qs over 16 clusters (rotate-reduce, 16-periodic)
            float t1r = Qv + dppf<0x128>(Qv);
            float t2r = t1r + dppf<0x124>(t1r);
            float t3r = t2r + dppf<0x122>(t2r);
            float qsv = t3r + dppf<0x121>(t3r);
            fqv[si] = Qv * rcp_fast(qsv);
            float xo = xb;
            xo = fmaf(dw[0], z , xo);
            xo = fmaf(dw[1], z1, xo);
            xo = fmaf(dw[2], z2, xo);
            xo = fmaf(dw[3], z3, xo);
            xo = fmaf(dw[4], z4, xo);
            xo = fmaf(dw[5], z5, xo);
            xo = fmaf(dw[6], z6, xo);
            xo = fmaf(dw[7], z7, xo);
            xv[si] = xo;
          }
          // fq store: rows fr, fr+4; col kk (r12-validated select tree)
          float a0 = (lane&16)? fqv[1]:fqv[0];
          float a1 = (lane&16)? fqv[3]:fqv[2];
          float vA = (lane&32)? a1:a0;
          float b0 = (lane&16)? fqv[5]:fqv[4];
          float b1 = (lane&16)? fqv[7]:fqv[6];
          float vB = (lane&32)? b1:b0;
          fqb[(size_t)(base_t+s0+fr)*K_ + kk] = vA;
          fqb[(size_t)(base_t+s0+4+fr)*K_ + kk] = vB;
          // xr store (r12-validated)
          float c0 = (lane&16)? xv[1]:xv[0];
          float c1 = (lane&16)? xv[3]:xv[2];
          float xA = (lane&32)? c1:c0;
          float d0 = (lane&16)? xv[5]:xv[4];
          float d1 = (lane&16)? xv[7]:xv[6];
          float xB = (lane&32)? d1:d0;
          if (kk < 10){
            xrb[(size_t)(base_t+s0+fr)*F_ + kk] = xA;
            xrb[(size_t)(base_t+s0+4+fr)*F_ + kk] = xB;
          }
        }
      }
      asm volatile("s_waitcnt lgkmcnt(0)\ns_barrier" ::: "memory");
    }
  } else {
    // ---------------- Wave E (wv==4): conv + W_ih1 -> g1 ring (SIMD0) -------
    const int sg = lane >> 3;           // step-in-group
    float cw[F_];
    #pragma unroll
    for (int f=0;f<F_;++f) cw[f] = conv_w[u*F_+f];
    const float cb = conv_b[u];
    float wi[4][8], bi[4];
    #pragma unroll
    for (int q=0;q<4;++q){
      const int row = q*8+u;
      const float Sq = (q==2)? (-2.f*LOG2E) : (-LOG2E);
      #pragma unroll
      for (int j=0;j<8;++j) wi[q][j] = w_ih1[row*F1_+j]*Sq;
      bi[q] = (b_ih1[row]+b_hh1[row])*Sq;
    }
    const float* xbp = x + (size_t)b*T_*F_;
    for (int k=0;k<NC+4;++k){
      if (k < NC){
        float* gp = &g1r[(k&1)*GCHUNK];
        for (int p=0;p<8;++p){
          const int s = p*8+sg;
          const float2* xp = (const float2*)(xbp + (size_t)(k*CHUNK+s)*F_);
          float2 xv0=xp[0], xv1=xp[1], xv2=xp[2], xv3=xp[3], xv4=xp[4];
          float enc = cb;
          enc = fmaf(cw[0],xv0.x,enc); enc = fmaf(cw[1],xv0.y,enc);
          enc = fmaf(cw[2],xv1.x,enc); enc = fmaf(cw[3],xv1.y,enc);
          enc = fmaf(cw[4],xv2.x,enc); enc = fmaf(cw[5],xv2.y,enc);
          enc = fmaf(cw[6],xv3.x,enc); enc = fmaf(cw[7],xv3.y,enc);
          enc = fmaf(cw[8],xv4.x,enc); enc = fmaf(cw[9],xv4.y,enc);
          enc = enc > 0.f ? enc : 0.01f*enc;    // leaky_relu
          esc[(sg<<3)+u] = enc;                 // wave-internal exchange
          float4 eA = *(const float4*)&esc[sg<<3];
          float4 eB = *(const float4*)&esc[(sg<<3)+4];
          #pragma unroll
          for (int q=0;q<4;++q){
            float pq = bi[q];
            pq = fmaf(wi[q][0],eA.x,pq); pq = fmaf(wi[q][1],eA.y,pq);
            pq = fmaf(wi[q][2],eA.z,pq); pq = fmaf(wi[q][3],eA.w,pq);
            pq = fmaf(wi[q][4],eB.x,pq); pq = fmaf(wi[q][5],eB.y,pq);
            pq = fmaf(wi[q][6],eB.z,pq); pq = fmaf(wi[q][7],eB.w,pq);
            gp[p*GBURST + (q*8+u)*GSTRIDE + sg] = pq;
          }
        }
      }
      asm volatile("s_waitcnt lgkmcnt(0)\ns_barrier" ::: "memory");
    }
  }
}

// ---------------- Kernel 4: fp only ----------------------------------------
__global__ __launch_bounds__(256) void k4_fp(const float* __restrict__ zout,
    const float* __restrict__ centers, const float* __restrict__ Sws,
    float* __restrict__ fp)
{
  int idx = blockIdx.x*256 + threadIdx.x;
  if (idx >= B_*T_) return;
  int b = idx >> 13;   // /T_
  float zv[H2_]; float zz=0.f;
  const float* zp = zout + (size_t)idx*H2_;
  #pragma unroll
  for (int j=0;j<H2_;++j){ zv[j]=zp[j]; zz+=zv[j]*zv[j]; }
  float P[K_]; float ps=0.f;
  #pragma unroll
  for (int k=0;k<K_;++k){
    float d = zz;
    #pragma unroll
    for (int j=0;j<H2_;++j){ float c=centers[k*H2_+j]; d += c*c - 2.f*c*zv[j]; }
    float q = rcp_fast(1.f+d);
    float p = q*q*rcp_fast(Sws[b*K_+k]);
    P[k]=p; ps+=p;
  }
  float ip = rcp_fast(ps);
  float4* fpp = (float4*)(fp + (size_t)idx*K_);
  #pragma unroll
  for (int c=0;c<4;++c){
    float4 vp;
    vp.x=P[4*c+0]*ip; vp.y=P[4*c+1]*ip; vp.z=P[4*c+2]*ip; vp.w=P[4*c+3]*ip;
    fpp[c]=vp;
  }
}

extern "C" void kernel_launch(void* const* d_in, const int* in_sizes, int n_in,
                              void* d_out, int out_size, void* d_ws, size_t ws_size,
                              hipStream_t stream)
{
  (void)in_sizes; (void)n_in; (void)out_size; (void)ws_size;
  const float* x      = (const float*)d_in[0];
  const float* conv_w = (const float*)d_in[1];
  const float* conv_b = (const float*)d_in[2];
  const float* w_ih1  = (const float*)d_in[3];
  const float* w_hh1  = (const float*)d_in[4];
  const float* b_ih1  = (const float*)d_in[5];
  const float* b_hh1  = (const float*)d_in[6];
  const float* w_ih2  = (const float*)d_in[7];
  const float* w_hh2  = (const float*)d_in[8];
  const float* b_ih2  = (const float*)d_in[9];
  const float* b_hh2  = (const float*)d_in[10];
  const float* dec_w  = (const float*)d_in[11];
  const float* dec_b  = (const float*)d_in[12];
  const float* centers= (const float*)d_in[13];

  float* out = (float*)d_out;
  float* z   = out;                              // [B,T,7]
  float* xr  = out + (size_t)B_*T_*H2_;          // [B,T,10]
  float* fp  = xr  + (size_t)B_*T_*F_;           // [B,T,16]
  float* fq  = fp  + (size_t)B_*T_*K_;           // [B,T,16]

  float* Sws = (float*)d_ws;                     // [B,16] column sums

  k2_lstm<<<dim3(B_), dim3(384), 0, stream>>>(x, conv_w, conv_b,
      w_ih1, b_ih1, b_hh1, w_hh1, w_ih2, w_hh2, b_ih2, b_hh2,
      centers, dec_w, dec_b, z, xr, fq, Sws);
  k4_fp<<<dim3((B_*T_)/256), dim3(256), 0, stream>>>(z, centers, Sws, fp);
}

// Round 17
// 754.688 us; speedup vs baseline: 1.4653x; 1.4653x over previous
//
#include <hip/hip_runtime.h>
#include <cstdint>
#include <cstddef>

#define B_ 128
#define T_ 8192
#define F_ 10
#define F1_ 8
#define H1_ 8
#define H2_ 7
#define K_ 16
#define CHUNK 64
#define NC (T_/CHUNK)   // 128

#define LOG2E 1.4426950408889634f

__device__ __forceinline__ float exp2_fast(float x){ float r; asm("v_exp_f32 %0, %1" : "=v"(r) : "v"(x)); return r; }
__device__ __forceinline__ float rcp_fast(float x){ float r; asm("v_rcp_f32 %0, %1" : "=v"(r) : "v"(x)); return r; }
template<int CTRL>
__device__ __forceinline__ float dppf(float x){
  return __int_as_float(__builtin_amdgcn_update_dpp(0, __float_as_int(x), CTRL, 0xF, 0xF, true));
}
// row_ror:m -> lane i reads lane (i-m)&15; on 8-periodic data = h[(u-m)&7].
// Weights indexed (u+8-m)&7 (direction validated r9->r10).
#define ROR(m) (0x120+(m))
#define WIDX(u,m) (((u)+8-(m))&7)
__device__ __forceinline__ float ror8(float x){ return dppf<0x128>(x); }
typedef int v2i_t __attribute__((ext_vector_type(2)));

// Burst rings use ROW STRIDE 12 floats (48B, 16B-aligned for b128):
// bank start = (row*12)&31 covers all 32 banks every 8 rows -> <=2-way
// (free, m136). Stride-8 was an 8-16-way conflict on the chain waves'
// burst reads (r13: 9.4M conflict cycles; r15: 3.1M).
#define GSTRIDE 12              // g1r row stride (floats)
#define GBURST  (32*GSTRIDE)    // 384: one burst = 32 rows
#define GCHUNK  (8*GBURST)      // 3072: one chunk slot
#define FSTRIDE 12              // ffr row stride
#define FBURST  (64*FSTRIDE)    // 768
#define FCHUNK  (8*FBURST)      // 6144

// ---------------- Kernel 2: 5-wave pipelined fused network -----------------
// wv0 = C: tanh(h1)+W_ih2 projection -> ff ring.
// wv1 = A: LSTM1 recurrence (bases from g1 ring, BURST reads) -> h1 ring.
// wv2 = B: LSTM2 recurrence (bases from ff ring, BURST reads) -> h2 ring.
// wv3 = D: tanh(h2) -> z stores + fused S[b,k] column sums (r13 scope --
//          fq/xr in D paces the barrier at +220us, r12/r14-confirmed;
//          a 6th wave for fq/xr pairs a helper with a chain SIMD and
//          costs +380us, r16-confirmed: 5 waves is the optimum).
// wv4 = E: conv encoder + W_ih1 projection -> g1 ring (burst-major).
// Rings depth-2 by chunk parity. Iteration k: E makes g1[k], A makes
// h1[k-1], C makes ff[k-2], B makes h2[k-3], D consumes h2[k-4].
// One lgkmcnt(0)+s_barrier per iteration, all 5 waves.
// Chain algebra/lane layout identical to r10 (validated).
__global__ __launch_bounds__(320,1) void k2_lstm(
    const float* __restrict__ x,
    const float* __restrict__ conv_w, const float* __restrict__ conv_b,
    const float* __restrict__ w_ih1, const float* __restrict__ b_ih1,
    const float* __restrict__ b_hh1, const float* __restrict__ w_hh1,
    const float* __restrict__ w_ih2, const float* __restrict__ w_hh2,
    const float* __restrict__ b_ih2, const float* __restrict__ b_hh2,
    const float* __restrict__ centers,
    float* __restrict__ zout, float* __restrict__ Sws)
{
  __shared__ float h1r[2*CHUNK*64];   // 32 KB raw h1  [slot][s][lane]
  __shared__ float ffr[2*FCHUNK];     // 48 KB ff      [slot][s>>3][lane][s&7] str12
  __shared__ float h2r[2*CHUNK*64];   // 32 KB raw h2  [slot][s][lane]
  __shared__ float g1r[2*GCHUNK];     // 24 KB g1 pre  [slot][s>>3][row][s&7] str12
  __shared__ float esc[64];           // E's enc exchange scratch
  const int b = blockIdx.x;
  const int tid = threadIdx.x;
  const int wv = tid >> 6;
  const int lane = tid & 63;
  const int u = lane & 7;
  const bool c2 = (lane >> 3) & 1;
  const bool up = (lane >> 5) & 1;
  const bool isg = (c2 && !up);
  const float A2 = isg ? (-2.f*LOG2E) : 0.5f;
  const float D_ = isg ? ( 2.f*LOG2E) : 0.f;
  const float Sx = isg ? (-2.f*LOG2E) : (-LOG2E);

  if (wv == 1){
    // ---------------- Wave A: LSTM1 recurrence ----------------
    const int prow = u + (c2 ? 16 : 0) + (up ? 8 : 0);     // W1 rows i|f|g|o
    float wp[8];
    #pragma unroll
    for (int m=0;m<8;++m) wp[m] = w_hh1[prow*8 + WIDX(u,m)] * Sx;
    float hq=0.f, csq=0.f;
    for (int k=0;k<NC+4;++k){
      if (k>=1 && k<NC+1){
        const int ck = k-1;
        const float* g1p = &g1r[(ck&1)*GCHUNK];
        float* hp = &h1r[(ck&1)*CHUNK*64];
        float4 cA = *(const float4*)&g1p[prow*GSTRIDE];
        float4 cB = *(const float4*)&g1p[prow*GSTRIDE+4];
        for (int j=0;j<8;++j){
          const int jn = (j<7) ? j+1 : 7;
          float4 nA = *(const float4*)&g1p[jn*GBURST + prow*GSTRIDE];
          float4 nB = *(const float4*)&g1p[jn*GBURST + prow*GSTRIDE+4];
          #pragma unroll
          for (int si=0;si<8;++si){
            const int s = (j<<3)+si;
            float pre = (si<4) ? (&cA.x)[si] : (&cB.x)[si-4];
            float x1 = dppf<ROR(1)>(hq);
            float x2 = dppf<ROR(2)>(hq);
            float x3 = dppf<ROR(3)>(hq);
            float x4 = dppf<ROR(4)>(hq);
            float x5 = dppf<ROR(5)>(hq);
            float x6 = dppf<ROR(6)>(hq);
            float x7 = dppf<ROR(7)>(hq);
            float A0 = fmaf(wp[0], hq, pre);
            A0 = fmaf(wp[4], x4, A0);
            float p2 = wp[2]*x2;
            float p3 = wp[3]*x3;
            A0 = fmaf(wp[1], x1, A0);
            float P2 = fmaf(wp[6], x6, p2);
            float P3 = fmaf(wp[7], x7, p3);
            float p5 = wp[5]*x5;
            A0 = A0 + p5;
            float g = A0 + (P2+P3);
            float e = exp2_fast(g);
            float tg = fmaf(e, 0.5f, 0.5f);
            float r = rcp_fast(tg);
            float y = fmaf(A2, r, D_);
            v2i_t pr = __builtin_amdgcn_permlane32_swap(__float_as_int(y), __float_as_int(y), false, false);
            float lov = __int_as_float(pr.x);
            float hiv = __int_as_float(pr.y);
            float IG = lov * ror8(lov);
            float HR = ror8(hiv);
            float Fv = c2 ? HR : hiv;
            float Ov = c2 ? hiv : HR;
            float cs = fmaf(Fv, csq, IG);
            float e2 = exp2_fast(cs);
            float t2 = fmaf(e2, 0.5f, 0.5f);
            float r2v = rcp_fast(t2);
            float hn = fmaf(Ov, r2v, -Ov);
            csq = cs; hq = hn;
            hp[(s<<6)+lane] = hn;
          }
          cA = nA; cB = nB;
        }
      }
      asm volatile("s_waitcnt lgkmcnt(0)\ns_barrier" ::: "memory");
    }
  } else if (wv == 2){
    // ---------------- Wave B: LSTM2 recurrence ----------------
    const int r2 = u + (c2 ? 14 : 0) + (up ? 7 : 0);       // W2 rows (H2=7)
    float wb[8];
    #pragma unroll
    for (int m=0;m<8;++m) wb[m] = 0.f;
    if (u < 7){
      #pragma unroll
      for (int m=0;m<8;++m){
        int jm = WIDX(u,m);
        wb[m] = (jm<7) ? w_hh2[r2*7+jm]*Sx : 0.f;
      }
    }
    float hq=0.f, csq=0.f;
    for (int k=0;k<NC+4;++k){
      if (k>=3 && k<NC+3){
        const int ck = k-3;
        const float* fp_ = &ffr[(ck&1)*FCHUNK];
        float* hp = &h2r[(ck&1)*CHUNK*64];
        float4 cA = *(const float4*)&fp_[lane*FSTRIDE];
        float4 cB = *(const float4*)&fp_[lane*FSTRIDE+4];
        for (int j=0;j<8;++j){
          const int jn = (j<7) ? j+1 : 7;
          float4 nA = *(const float4*)&fp_[jn*FBURST + lane*FSTRIDE];
          float4 nB = *(const float4*)&fp_[jn*FBURST + lane*FSTRIDE+4];
          #pragma unroll
          for (int si=0;si<8;++si){
            const int s = (j<<3)+si;
            float ffv = (si<4) ? (&cA.x)[si] : (&cB.x)[si-4];
            float x1 = dppf<ROR(1)>(hq);
            float x2 = dppf<ROR(2)>(hq);
            float x3 = dppf<ROR(3)>(hq);
            float x4 = dppf<ROR(4)>(hq);
            float x5 = dppf<ROR(5)>(hq);
            float x6 = dppf<ROR(6)>(hq);
            float x7 = dppf<ROR(7)>(hq);
            float A0 = fmaf(wb[0], hq, ffv);
            A0 = fmaf(wb[4], x4, A0);
            float p2 = wb[2]*x2;
            float p3 = wb[3]*x3;
            A0 = fmaf(wb[1], x1, A0);
            float P2 = fmaf(wb[6], x6, p2);
            float P3 = fmaf(wb[7], x7, p3);
            float p5 = wb[5]*x5;
            A0 = A0 + p5;
            float g = A0 + (P2+P3);
            float e = exp2_fast(g);
            float tg = fmaf(e, 0.5f, 0.5f);
            float r = rcp_fast(tg);
            float y = fmaf(A2, r, D_);
            v2i_t pr = __builtin_amdgcn_permlane32_swap(__float_as_int(y), __float_as_int(y), false, false);
            float lov = __int_as_float(pr.x);
            float hiv = __int_as_float(pr.y);
            float IG = lov * ror8(lov);
            float HR = ror8(hiv);
            float Fv = c2 ? HR : hiv;
            float Ov = c2 ? hiv : HR;
            float cs = fmaf(Fv, csq, IG);
            float e2 = exp2_fast(cs);
            float t2 = fmaf(e2, 0.5f, 0.5f);
            float r2v = rcp_fast(t2);
            float hn = fmaf(Ov, r2v, -Ov);
            csq = cs; hq = hn;
            hp[(s<<6)+lane] = hn;
          }
          cA = nA; cB = nB;
        }
      }
      asm volatile("s_waitcnt lgkmcnt(0)\ns_barrier" ::: "memory");
    }
  } else if (wv == 0){
    // ---------------- Wave C: ff projection from h1 ----------------
    const int r2 = u + (c2 ? 14 : 0) + (up ? 7 : 0);
    float wff[8]; float pre2C = 0.f;
    #pragma unroll
    for (int m=0;m<8;++m) wff[m] = 0.f;
    if (u < 7){
      #pragma unroll
      for (int m=0;m<8;++m) wff[m] = w_ih2[r2*8 + WIDX(u,m)] * Sx;
      pre2C = (b_ih2[r2]+b_hh2[r2])*Sx;
    }
    for (int k=0;k<NC+4;++k){
      if (k>=2 && k<NC+2){
        const int ck = k-2;
        const float* h1p = &h1r[(ck&1)*CHUNK*64];
        float* ffp = &ffr[(ck&1)*FCHUNK];
        for (int s0=0;s0<CHUNK;s0+=8){
          #pragma unroll
          for (int si=0;si<8;++si){
            const int s = s0+si;
            float hv = h1p[(s<<6)+lane];
            float e3 = exp2_fast(hv * (-2.f*LOG2E));
            float t3 = fmaf(e3, 0.5f, 0.5f);
            float th = rcp_fast(t3) - 1.f;    // tanh(h1), replicated th[u]
            float f1 = dppf<ROR(1)>(th);
            float f2 = dppf<ROR(2)>(th);
            float f3 = dppf<ROR(3)>(th);
            float f4 = dppf<ROR(4)>(th);
            float f5 = dppf<ROR(5)>(th);
            float f6 = dppf<ROR(6)>(th);
            float f7 = dppf<ROR(7)>(th);
            float F0 = fmaf(wff[0], th, pre2C);
            F0 = fmaf(wff[4], f4, F0);
            float q2 = wff[2]*f2;
            float q3 = wff[3]*f3;
            F0 = fmaf(wff[1], f1, F0);
            q2 = fmaf(wff[6], f6, q2);
            q3 = fmaf(wff[7], f7, q3);
            float q5 = wff[5]*f5;
            F0 = F0 + q5;
            float ffv = F0 + (q2+q3);
            // burst-major stride-12: [s>>3][lane][s&7]
            ffp[(s0>>3)*FBURST + lane*FSTRIDE + si] = ffv;
          }
        }
      }
      asm volatile("s_waitcnt lgkmcnt(0)\ns_barrier" ::: "memory");
    }
  } else if (wv == 3){
    // ---------------- Wave D: z stores + fused S (r13 scope) ----------------
    const int kk = lane & 15;
    float ckp[8]; float accS = 0.f;
    #pragma unroll
    for (int m=0;m<8;++m){
      int j = WIDX(u,m);
      ckp[m] = (j<7) ? centers[kk*H2_ + j] : 0.f;   // z_7 == 0 exactly
    }
    float* zb = zout + (size_t)b*T_*H2_;
    const int srow = lane >> 3;
    for (int k=0;k<NC+4;++k){
      if (k>=4 && k<NC+4){
        const int ck = k-4;
        const float* h2p = &h2r[(ck&1)*CHUNK*64];
        const int base_t = ck*CHUNK;
        for (int s0=0;s0<CHUNK;s0+=8){
          float zs[8];
          #pragma unroll
          for (int si=0;si<8;++si){
            float hv = h2p[((s0+si)<<6)+lane];
            float e3 = exp2_fast(hv * (-2.f*LOG2E));
            float t3 = fmaf(e3, 0.5f, 0.5f);
            float z = rcp_fast(t3) - 1.f;     // z = tanh(h2), replicated
            zs[si] = z;
            float z1 = dppf<ROR(1)>(z);
            float z2 = dppf<ROR(2)>(z);
            float z3 = dppf<ROR(3)>(z);
            float z4 = dppf<ROR(4)>(z);
            float z5 = dppf<ROR(5)>(z);
            float z6 = dppf<ROR(6)>(z);
            float z7 = dppf<ROR(7)>(z);
            float d = 1.f;
            float t0 = z  - ckp[0]; d = fmaf(t0,t0,d);
            float u1 = z1 - ckp[1]; d = fmaf(u1,u1,d);
            float u2 = z2 - ckp[2]; d = fmaf(u2,u2,d);
            float u3 = z3 - ckp[3]; d = fmaf(u3,u3,d);
            float u4 = z4 - ckp[4]; d = fmaf(u4,u4,d);
            float u5 = z5 - ckp[5]; d = fmaf(u5,u5,d);
            float u6 = z6 - ckp[6]; d = fmaf(u6,u6,d);
            float u7 = z7 - ckp[7]; d = fmaf(u7,u7,d);
            accS += rcp_fast(d);
          }
          float v0 = ((lane>>3)&1) ? zs[1] : zs[0];
          float v1 = ((lane>>3)&1) ? zs[3] : zs[2];
          float v2 = ((lane>>3)&1) ? zs[5] : zs[4];
          float v3 = ((lane>>3)&1) ? zs[7] : zs[6];
          float w0 = ((lane>>4)&1) ? v1 : v0;
          float w1 = ((lane>>4)&1) ? v3 : v2;
          float zo = ((lane>>5)&1) ? w1 : w0;
          if (u < 7) zb[(size_t)(base_t + s0 + srow)*H2_ + u] = zo;
        }
      }
      asm volatile("s_waitcnt lgkmcnt(0)\ns_barrier" ::: "memory");
    }
    if (lane < 16) Sws[b*K_ + lane] = accS;
  } else {
    // ---------------- Wave E: conv + W_ih1 projection -> g1 ring ------------
    const int sg = lane >> 3;           // step-in-group
    float cw[F_];
    #pragma unroll
    for (int f=0;f<F_;++f) cw[f] = conv_w[u*F_+f];
    const float cb = conv_b[u];
    float wi[4][8], bi[4];
    #pragma unroll
    for (int q=0;q<4;++q){
      const int row = q*8+u;
      const float Sq = (q==2)? (-2.f*LOG2E) : (-LOG2E);
      #pragma unroll
      for (int j=0;j<8;++j) wi[q][j] = w_ih1[row*F1_+j]*Sq;
      bi[q] = (b_ih1[row]+b_hh1[row])*Sq;
    }
    const float* xbp = x + (size_t)b*T_*F_;
    for (int k=0;k<NC+4;++k){
      if (k < NC){
        float* gp = &g1r[(k&1)*GCHUNK];
        for (int p=0;p<8;++p){
          const int s = p*8+sg;
          const float2* xp = (const float2*)(xbp + (size_t)(k*CHUNK+s)*F_);
          float2 xv0=xp[0], xv1=xp[1], xv2=xp[2], xv3=xp[3], xv4=xp[4];
          float enc = cb;
          enc = fmaf(cw[0],xv0.x,enc); enc = fmaf(cw[1],xv0.y,enc);
          enc = fmaf(cw[2],xv1.x,enc); enc = fmaf(cw[3],xv1.y,enc);
          enc = fmaf(cw[4],xv2.x,enc); enc = fmaf(cw[5],xv2.y,enc);
          enc = fmaf(cw[6],xv3.x,enc); enc = fmaf(cw[7],xv3.y,enc);
          enc = fmaf(cw[8],xv4.x,enc); enc = fmaf(cw[9],xv4.y,enc);
          enc = enc > 0.f ? enc : 0.01f*enc;    // leaky_relu
          esc[(sg<<3)+u] = enc;                 // wave-internal exchange
          float4 eA = *(const float4*)&esc[sg<<3];
          float4 eB = *(const float4*)&esc[(sg<<3)+4];
          #pragma unroll
          for (int q=0;q<4;++q){
            float pq = bi[q];
            pq = fmaf(wi[q][0],eA.x,pq); pq = fmaf(wi[q][1],eA.y,pq);
            pq = fmaf(wi[q][2],eA.z,pq); pq = fmaf(wi[q][3],eA.w,pq);
            pq = fmaf(wi[q][4],eB.x,pq); pq = fmaf(wi[q][5],eB.y,pq);
            pq = fmaf(wi[q][6],eB.z,pq); pq = fmaf(wi[q][7],eB.w,pq);
            // burst-major stride-12: [p][row=q*8+u][sg] (<=2-way banks)
            gp[p*GBURST + (q*8+u)*GSTRIDE + sg] = pq;
          }
        }
      }
      asm volatile("s_waitcnt lgkmcnt(0)\ns_barrier" ::: "memory");
    }
  }
}

// ---------------- Kernel 4: decoder + fq/fp (r13-validated) ----------------
__global__ __launch_bounds__(256) void k4_out(const float* __restrict__ zout,
    const float* __restrict__ dec_w, const float* __restrict__ dec_b,
    const float* __restrict__ centers, const float* __restrict__ Sws,
    float* __restrict__ xr, float* __restrict__ fp, float* __restrict__ fq)
{
  int idx = blockIdx.x*256 + threadIdx.x;
  if (idx >= B_*T_) return;
  int b = idx >> 13;   // /T_
  float zv[H2_]; float zz=0.f;
  const float* zp = zout + (size_t)idx*H2_;
  #pragma unroll
  for (int j=0;j<H2_;++j){ zv[j]=zp[j]; zz+=zv[j]*zv[j]; }
  float2 xo[5];
  #pragma unroll
  for (int f=0; f<F_; ++f){
    float a = dec_b[f];
    #pragma unroll
    for (int c=0;c<H2_;++c) a += zv[c]*dec_w[c*F_+f];
    (&xo[0].x)[f] = a;
  }
  float2* xp2 = (float2*)(xr + (size_t)idx*F_);
  #pragma unroll
  for (int c=0;c<5;++c) xp2[c] = xo[c];

  float Q[K_], P[K_]; float qs=0.f, ps=0.f;
  #pragma unroll
  for (int k=0;k<K_;++k){
    float d = zz;
    #pragma unroll
    for (int j=0;j<H2_;++j){ float c=centers[k*H2_+j]; d += c*c - 2.f*c*zv[j]; }
    float q = rcp_fast(1.f+d);
    Q[k]=q; qs+=q;
    float p = q*q*rcp_fast(Sws[b*K_+k]);
    P[k]=p; ps+=p;
  }
  float iq = rcp_fast(qs), ip = rcp_fast(ps);
  float4* fqp = (float4*)(fq + (size_t)idx*K_);
  float4* fpp = (float4*)(fp + (size_t)idx*K_);
  #pragma unroll
  for (int c=0;c<4;++c){
    float4 vq, vp;
    vq.x=Q[4*c+0]*iq; vq.y=Q[4*c+1]*iq; vq.z=Q[4*c+2]*iq; vq.w=Q[4*c+3]*iq;
    vp.x=P[4*c+0]*ip; vp.y=P[4*c+1]*ip; vp.z=P[4*c+2]*ip; vp.w=P[4*c+3]*ip;
    fqp[c]=vq; fpp[c]=vp;
  }
}

extern "C" void kernel_launch(void* const* d_in, const int* in_sizes, int n_in,
                              void* d_out, int out_size, void* d_ws, size_t ws_size,
                              hipStream_t stream)
{
  (void)in_sizes; (void)n_in; (void)out_size; (void)ws_size;
  const float* x      = (const float*)d_in[0];
  const float* conv_w = (const float*)d_in[1];
  const float* conv_b = (const float*)d_in[2];
  const float* w_ih1  = (const float*)d_in[3];
  const float* w_hh1  = (const float*)d_in[4];
  const float* b_ih1  = (const float*)d_in[5];
  const float* b_hh1  = (const float*)d_in[6];
  const float* w_ih2  = (const float*)d_in[7];
  const float* w_hh2  = (const float*)d_in[8];
  const float* b_ih2  = (const float*)d_in[9];
  const float* b_hh2  = (const float*)d_in[10];
  const float* dec_w  = (const float*)d_in[11];
  const float* dec_b  = (const float*)d_in[12];
  const float* centers= (const float*)d_in[13];

  float* out = (float*)d_out;
  float* z   = out;                              // [B,T,7]
  float* xr  = out + (size_t)B_*T_*H2_;          // [B,T,10]
  float* fp  = xr  + (size_t)B_*T_*F_;           // [B,T,16]
  float* fq  = fp  + (size_t)B_*T_*K_;           // [B,T,16]

  float* Sws = (float*)d_ws;                     // [B,16] column sums

  k2_lstm<<<dim3(B_), dim3(320), 0, stream>>>(x, conv_w, conv_b,
      w_ih1, b_ih1, b_hh1, w_hh1, w_ih2, w_hh2, b_ih2, b_hh2,
      centers, z, Sws);
  k4_out<<<dim3((B_*T_)/256), dim3(256), 0, stream>>>(z, dec_w, dec_b,
      centers, Sws, xr, fp, fq);
}